// Round 14
// baseline (49.583 us; speedup 1.0000x reference)
//
#include <hip/hip_runtime.h>
#include <cstddef>

#define T_STEPS 128
#define D_IN    57
#define HDIM    64
#define ODIM    7
#define FAN     121
#define GK      7296          // floats per x row (128*57)
#define KTOT    7239          // 127*57 real G columns
#define KHALF   3648          // 64*57
#define GBYTES  ((size_t)HDIM * GK * 2)

typedef __attribute__((ext_vector_type(8))) short    short8;
typedef __attribute__((ext_vector_type(4))) float    f32x4;
typedef __attribute__((ext_vector_type(4))) unsigned uint4v;
typedef __attribute__((ext_vector_type(2))) unsigned uint2v;

#define MFMA(a,b,c) __builtin_amdgcn_mfma_f32_16x16x32_bf16((a),(b),(c),0,0,0)
#define DS_FENCE()  __builtin_amdgcn_sched_barrier(0x7F)

union FragU { short8 s8; unsigned u[4]; uint4v u4; };

__device__ inline unsigned short f2bf(float f) {
    __bf16 h = (__bf16)f;
    return __builtin_bit_cast(unsigned short, h);
}
__device__ inline float bf2f(unsigned short u) {
    return __builtin_bit_cast(float, (unsigned)u << 16);
}
__device__ inline unsigned pk2(float lo, float hi) {
    return ((unsigned)f2bf(hi) << 16) | (unsigned)f2bf(lo);
}
__device__ inline unsigned swz(unsigned b) {
    return b ^ (((b >> 7) & 7u) << 4);
}

// G fragment-linear byte offset for element (h, k)
__device__ inline size_t gfrag_off(int h, int k) {
    int ch = k >> 5, kk = k & 31;
    return (size_t)(((ch * 4 + (h >> 4)) * 64 + (kk >> 3) * 16 + (h & 15)) * 16 + (kk & 7) * 2);
}

__device__ inline short8 wfragX(const float* Wr, int kbase) {
    FragU f;
#pragma unroll
    for (int d = 0; d < 4; ++d) {
        int k0 = kbase + 2 * d, k1 = k0 + 1;
        float a = (k0 < D_IN) ? Wr[k0] : 0.0f;
        float b = (k1 < D_IN) ? Wr[k1] : 0.0f;
        f.u[d] = pk2(a, b);
    }
    return f.s8;
}
__device__ inline short8 wfragH(const float* Wr, int kbase) {
    FragU f;
#pragma unroll
    for (int d = 0; d < 4; ++d) { int k0 = kbase + 2 * d; f.u[d] = pk2(Wr[k0], Wr[k0 + 1]); }
    return f.s8;
}
__device__ inline short8 xfrag(const float* r) {
    FragU f;
#pragma unroll
    for (int d = 0; d < 4; ++d) f.u[d] = pk2(r[2 * d], r[2 * d + 1]);
    return f.s8;
}

struct XR { float a[8]; float b[8]; };
__device__ inline void loadx(XR& r, const float* xrow, int t, int q) {
    const float* p = xrow + t * D_IN;
#pragma unroll
    for (int i = 0; i < 8; ++i) r.a[i] = p[q * 8 + i];
    if (q == 3) {
        r.b[0] = p[56];
#pragma unroll
        for (int i = 1; i < 8; ++i) r.b[i] = 0.0f;
    } else {
#pragma unroll
        for (int i = 0; i < 8; ++i) r.b[i] = p[32 + q * 8 + i];
    }
}

// ===== prep (128 blocks): unchanged from R13 (fragment-linear G writeback) =====
__global__ __launch_bounds__(512, 1) void rnn_prep(
    const float* __restrict__ Wih, const float* __restrict__ bih, char* __restrict__ wsb)
{
    float* Sb = (float*)(wsb + GBYTES);
    const int t    = blockIdx.x;
    const int n    = 126 - t;
    const int tid  = threadIdx.x;
    const int lane = tid & 63, wid = tid >> 6;
    const int st   = lane & 15, q = lane >> 4;

    __shared__ __align__(16) unsigned short Arow[2][64][64];
    __shared__ __align__(16) unsigned short Acol[2][64][64];
    __shared__ __align__(16) unsigned short Ccol[2][64][64];
    __shared__ float Ub[64], Wb[64], Ptu[64][8], Ptw[64][8];

    {
        const int h  = tid & 63;
        const int k0 = (tid >> 6) * 8;
        unsigned ur[4], uc[4], ux[4];
#pragma unroll
        for (int d = 0; d < 4; ++d) {
            ur[d] = pk2(Wih[h * FAN + D_IN + k0 + 2 * d], Wih[h * FAN + D_IN + k0 + 2 * d + 1]);
            uc[d] = pk2(Wih[(k0 + 2 * d) * FAN + D_IN + h], Wih[(k0 + 2 * d + 1) * FAN + D_IN + h]);
            float e0 = (h < D_IN) ? Wih[(k0 + 2 * d) * FAN + h] : 0.0f;
            float e1 = (h < D_IN) ? Wih[(k0 + 2 * d + 1) * FAN + h] : 0.0f;
            ux[d] = pk2(e0, e1);
        }
        uint4v v;
        v[0] = ur[0]; v[1] = ur[1]; v[2] = ur[2]; v[3] = ur[3];
        *(uint4v*)((char*)Arow[0] + swz((unsigned)(h * 128 + k0 * 2))) = v;
        v[0] = uc[0]; v[1] = uc[1]; v[2] = uc[2]; v[3] = uc[3];
        *(uint4v*)((char*)Acol[0] + swz((unsigned)(h * 128 + k0 * 2))) = v;
        v[0] = ux[0]; v[1] = ux[1]; v[2] = ux[2]; v[3] = ux[3];
        *(uint4v*)((char*)Ccol[0] + swz((unsigned)(h * 128 + k0 * 2))) = v;
    }
    if (tid < 64) { Ub[tid] = bih[tid]; Wb[tid] = bih[tid]; }
    __syncthreads();

    int ab = 0, cb = 0;
    for (int i = 0; i < 7; ++i) {
        const bool domul = (t < 127) && ((n >> i) & 1);
        const bool dosq  = (i < 6);
        const char* Lr = (const char*)Arow[ab];
        f32x4 accM[2], accS[2];
#pragma unroll
        for (int e = 0; e < 2; ++e) {
            const int tt = wid * 2 + e, r = tt >> 2, c = tt & 3;
            FragU a0, a1;
            a0.u4 = *(const uint4v*)(Lr + swz((unsigned)((16 * r + st) * 128 + q * 16)));
            a1.u4 = *(const uint4v*)(Lr + swz((unsigned)((16 * r + st) * 128 + 64 + q * 16)));
            if (domul) {
                FragU b0, b1;
                b0.u4 = *(const uint4v*)((const char*)Ccol[cb] + swz((unsigned)((16 * c + st) * 128 + q * 16)));
                b1.u4 = *(const uint4v*)((const char*)Ccol[cb] + swz((unsigned)((16 * c + st) * 128 + 64 + q * 16)));
                f32x4 z = {0.f, 0.f, 0.f, 0.f};
                accM[e] = MFMA(a0.s8, b0.s8, z);
                accM[e] = MFMA(a1.s8, b1.s8, accM[e]);
            }
            if (dosq) {
                FragU b0, b1;
                b0.u4 = *(const uint4v*)((const char*)Acol[ab] + swz((unsigned)((16 * c + st) * 128 + q * 16)));
                b1.u4 = *(const uint4v*)((const char*)Acol[ab] + swz((unsigned)((16 * c + st) * 128 + 64 + q * 16)));
                f32x4 z = {0.f, 0.f, 0.f, 0.f};
                accS[e] = MFMA(a0.s8, b0.s8, z);
                accS[e] = MFMA(a1.s8, b1.s8, accS[e]);
            }
        }
        if (t == 127) {
            const int h = tid >> 3, p = tid & 7;
            FragU sr;
            sr.u4 = *(const uint4v*)(Lr + swz((unsigned)(h * 128 + p * 16)));
            float su = 0.0f, sw = 0.0f;
#pragma unroll
            for (int d2 = 0; d2 < 4; ++d2) {
                float e0 = bf2f((unsigned short)(sr.u[d2] & 0xFFFFu));
                float e1 = bf2f((unsigned short)(sr.u[d2] >> 16));
                su += e0 * Ub[8 * p + 2 * d2] + e1 * Ub[8 * p + 2 * d2 + 1];
                sw += e0 * Wb[8 * p + 2 * d2] + e1 * Wb[8 * p + 2 * d2 + 1];
            }
            Ptu[h][p] = su; Ptw[h][p] = sw;
        }
        if (domul) {
#pragma unroll
            for (int e = 0; e < 2; ++e) {
                const int tt = wid * 2 + e, r = tt >> 2, c = tt & 3;
                uint2v w; w[0] = pk2(accM[e][0], accM[e][1]); w[1] = pk2(accM[e][2], accM[e][3]);
                *(uint2v*)((char*)Ccol[cb ^ 1] + swz((unsigned)((16 * c + st) * 128 + (16 * r + 4 * q) * 2))) = w;
            }
        }
        if (dosq) {
#pragma unroll
            for (int e = 0; e < 2; ++e) {
                const int tt = wid * 2 + e, r = tt >> 2, c = tt & 3;
                uint2v w; w[0] = pk2(accS[e][0], accS[e][1]); w[1] = pk2(accS[e][2], accS[e][3]);
                *(uint2v*)((char*)Acol[ab ^ 1] + swz((unsigned)((16 * c + st) * 128 + (16 * r + 4 * q) * 2))) = w;
#pragma unroll
                for (int j = 0; j < 4; ++j)
                    *(unsigned short*)((char*)Arow[ab ^ 1]
                        + swz((unsigned)((16 * r + 4 * q + j) * 128 + (16 * c + st) * 2))) = f2bf(accS[e][j]);
            }
        }
        __syncthreads();
        if (t == 127) {
            if (tid < 64) {
                float su = Ub[tid], sw = 0.0f;
#pragma unroll
                for (int p = 0; p < 8; ++p) { su += Ptu[tid][p]; sw += Ptw[tid][p]; }
                Ub[tid] = su;
                Wb[tid] = sw;
            }
            __syncthreads();
        }
        if (domul) cb ^= 1;
        if (dosq)  ab ^= 1;
    }

    if (t < 127) {
        for (int idx = tid; idx < 64 * D_IN; idx += 512) {
            int h = idx / D_IN, c = idx - h * D_IN;
            unsigned short val =
                *(const unsigned short*)((const char*)Ccol[cb] + swz((unsigned)(c * 128 + h * 2)));
            *(unsigned short*)(wsb + gfrag_off(h, 57 * t + c)) = val;
        }
    } else {
        if (tid < 64) Sb[tid] = Ub[tid] - Wb[tid];
        for (int idx = tid; idx < 64 * (GK - KTOT); idx += 512) {
            int h = idx / (GK - KTOT), c = idx % (GK - KTOT);
            *(unsigned short*)(wsb + gfrag_off(h, KTOT + c)) = 0;
        }
    }
}

// ===== main: block = (32 seqs) x (K half); every G fragment feeds 2 seq-tiles (8 MFMA/chunk) =====
__global__ __launch_bounds__(1024, 1) void rnn_gemm_half(
    const float* __restrict__ x,
    const char*  __restrict__ wsb,
    float* __restrict__ Hpart,
    int*   __restrict__ flags,
    int B)
{
    const int tid  = threadIdx.x;
    const int wid  = tid >> 6, lane = tid & 63;
    const int st   = lane & 15, q = lane >> 4;
    const int half = blockIdx.x & 1;
    const int grp  = blockIdx.x >> 1;
    const int seq0 = grp * 32;

    __shared__ __align__(16) char XsB[2][2][16384];   // [buf][subtile T][bytes]
    __shared__ float Red[8][2048];                     // 64 KB
    __shared__ int   FlgL;

    if (tid == 0) FlgL = (seq0 + 32 > B) ? 1 : 0;      // partial group -> slow path

    int sw0 = seq0 + wid;      if (sw0 >= B) sw0 = B - 1;
    int sw1 = seq0 + 16 + wid; if (sw1 >= B) sw1 = B - 1;
    const float* xw0 = x + (size_t)sw0 * GK;
    const float* xw1 = x + (size_t)sw1 * GK;
    const int tbase0 = half * KHALF;

    bool vflag = false;
    f32x4 s0a, s0b, s1a, s1b; bool sact = false;
    const int sc_ = lane >> 2, sq_ = lane & 3;

    auto SLOAD = [&](int tile) {
        int nc = (tile < 7) ? 16 : 2;
        sact = (sc_ < nc);
        if (sact) {
            int k0 = tbase0 + tile * 512 + sc_ * 32 + sq_ * 8;
            s0a = *(const f32x4*)(xw0 + k0);
            s0b = *(const f32x4*)(xw0 + k0 + 4);
            s1a = *(const f32x4*)(xw1 + k0);
            s1b = *(const f32x4*)(xw1 + k0 + 4);
        }
    };
    auto SWRITE = [&](int tile, int buf) {
        if (sact) {
            int k0 = tbase0 + tile * 512 + sc_ * 32 + sq_ * 8;
            int r  = k0 % 57;
            int e  = (r == 0) ? 0 : 57 - r;
            if (e < 8) {
                float v0 = (e == 0) ? s0a[0] : (e == 1) ? s0a[1] : (e == 2) ? s0a[2]
                         : (e == 3) ? s0a[3] : (e == 4) ? s0b[0] : (e == 5) ? s0b[1]
                         : (e == 6) ? s0b[2] : s0b[3];
                float v1 = (e == 0) ? s1a[0] : (e == 1) ? s1a[1] : (e == 2) ? s1a[2]
                         : (e == 3) ? s1a[3] : (e == 4) ? s1b[0] : (e == 5) ? s1b[1]
                         : (e == 6) ? s1b[2] : s1b[3];
                vflag |= (v0 == -1.0f) | (v1 == -1.0f);
            }
            unsigned a = ((unsigned)((sc_ * 64 + sq_ * 16 + wid) * 16)) ^ ((unsigned)(sc_ & 7) << 4);
            uint4v wv;
            wv[0] = pk2(s0a[0], s0a[1]); wv[1] = pk2(s0a[2], s0a[3]);
            wv[2] = pk2(s0b[0], s0b[1]); wv[3] = pk2(s0b[2], s0b[3]);
            *(uint4v*)(&XsB[buf][0][a]) = wv;
            wv[0] = pk2(s1a[0], s1a[1]); wv[1] = pk2(s1a[2], s1a[3]);
            wv[2] = pk2(s1b[0], s1b[1]); wv[3] = pk2(s1b[2], s1b[3]);
            *(uint4v*)(&XsB[buf][1][a]) = wv;
        }
    };

    f32x4 acc0[4], acc1[4];
#pragma unroll
    for (int n = 0; n < 4; ++n) { acc0[n] = (f32x4){0,0,0,0}; acc1[n] = (f32x4){0,0,0,0}; }

    SLOAD(0); SWRITE(0, 0);
    __syncthreads();

#pragma unroll 1
    for (int tile = 0; tile < 8; ++tile) {
        int buf = tile & 1;
        if (tile + 1 < 8) SLOAD(tile + 1);
        int nc = (tile < 7) ? 16 : 2;
        if (wid < nc) {
            unsigned a = ((unsigned)((wid * 64 + lane) * 16)) ^ ((unsigned)(wid & 7) << 4);
            FragU bx0, bx1;
            bx0.u4 = *(const uint4v*)(&XsB[buf][0][a]);
            bx1.u4 = *(const uint4v*)(&XsB[buf][1][a]);
            int cabs = half * 114 + tile * 16 + wid;
            const char* gb = wsb + ((size_t)cabs << 12);
            FragU a0, a1, a2, a3;
            a0.u4 = *(const uint4v*)(gb + 0 * 1024 + lane * 16);
            a1.u4 = *(const uint4v*)(gb + 1 * 1024 + lane * 16);
            a2.u4 = *(const uint4v*)(gb + 2 * 1024 + lane * 16);
            a3.u4 = *(const uint4v*)(gb + 3 * 1024 + lane * 16);
            acc0[0] = MFMA(a0.s8, bx0.s8, acc0[0]);
            acc1[0] = MFMA(a0.s8, bx1.s8, acc1[0]);
            acc0[1] = MFMA(a1.s8, bx0.s8, acc0[1]);
            acc1[1] = MFMA(a1.s8, bx1.s8, acc1[1]);
            acc0[2] = MFMA(a2.s8, bx0.s8, acc0[2]);
            acc1[2] = MFMA(a2.s8, bx1.s8, acc1[2]);
            acc0[3] = MFMA(a3.s8, bx0.s8, acc0[3]);
            acc1[3] = MFMA(a3.s8, bx1.s8, acc1[3]);
        }
        if (tile + 1 < 8) SWRITE(tile + 1, buf ^ 1);
        __syncthreads();
    }

    if (vflag) atomicOr(&FlgL, 1);

    // two-round reduction into Red[8][2048]; Hpart layout: idx = hid*32 + (T*16+st)
    if (wid < 8) {
#pragma unroll
        for (int n = 0; n < 4; ++n)
#pragma unroll
            for (int jj = 0; jj < 4; ++jj) {
                int row = (16 * n + 4 * q + jj) * 32 + st;
                Red[wid][row]      = acc0[n][jj];
                Red[wid][row + 16] = acc1[n][jj];
            }
    }
    __syncthreads();
    if (wid >= 8) {
#pragma unroll
        for (int n = 0; n < 4; ++n)
#pragma unroll
            for (int jj = 0; jj < 4; ++jj) {
                int row = (16 * n + 4 * q + jj) * 32 + st;
                Red[wid - 8][row]      += acc0[n][jj];
                Red[wid - 8][row + 16] += acc1[n][jj];
            }
    }
    __syncthreads();
    for (int i = tid; i < 2048; i += 1024) {
        float s = 0;
#pragma unroll
        for (int w = 0; w < 8; ++w) s += Red[w][i];
        Hpart[(size_t)blockIdx.x * 2048 + i] = s;
    }
    if (tid == 0) flags[blockIdx.x] = FlgL;
}

// ===== epilogue (grid = ngroups of 32 seqs, 256 thr) =====
__global__ __launch_bounds__(256, 1) void rnn_epilogue(
    const float* __restrict__ x,
    const float* __restrict__ Wih,
    const float* __restrict__ bih,
    const float* __restrict__ Wio,
    const float* __restrict__ bio,
    const char*  __restrict__ wsb,
    const float* __restrict__ Hpart,
    const int*   __restrict__ flags,
    float* __restrict__ out,
    int B)
{
    const float* Sb = (const float*)(wsb + GBYTES);
    const int grp  = blockIdx.x;
    const int seq0 = grp * 32;
    const int tid  = threadIdx.x;

    __shared__ float Hp[32][68];
    __shared__ float Lg[32][8];
    __shared__ int   Tl[32];
    __shared__ unsigned short Msub[32][8];
    __shared__ unsigned Mm[32][4];
    __shared__ __align__(16) unsigned short HsW[2][1024];

    const float* p0 = Hpart + (size_t)(2 * grp)     * 2048;
    const float* p1 = Hpart + (size_t)(2 * grp + 1) * 2048;
    for (int i = tid; i < 2048; i += 256) {
        int hid = i >> 5, sl = i & 31;
        Hp[sl][hid] = p0[i] + p1[i] + Sb[hid];
    }
    if (tid < 32) Tl[tid] = 127;
    const int bad = flags[2 * grp] | flags[2 * grp + 1];
    __syncthreads();

    if (bad) {
        {
            int sl = tid & 31, tg = tid >> 5;
            int sc = seq0 + sl; if (sc >= B) sc = B - 1;
            const float* xr = x + (size_t)sc * GK;
            unsigned m = 0;
#pragma unroll
            for (int i = 0; i < 16; ++i)
                m |= ((xr[(size_t)(16 * tg + i) * D_IN] != -1.0f) ? 1u : 0u) << i;
            Msub[sl][tg] = (unsigned short)m;
        }
        __syncthreads();
        if (tid < 32) {
            unsigned mk[4];
#pragma unroll
            for (int j = 0; j < 4; ++j)
                mk[j] = (unsigned)Msub[tid][2 * j] | ((unsigned)Msub[tid][2 * j + 1] << 16);
            Mm[tid][0] = mk[0]; Mm[tid][1] = mk[1]; Mm[tid][2] = mk[2]; Mm[tid][3] = mk[3];
            int tl;
            if (mk[3])      tl = 127 - __builtin_clz(mk[3]);
            else if (mk[2]) tl =  95 - __builtin_clz(mk[2]);
            else if (mk[1]) tl =  63 - __builtin_clz(mk[1]);
            else if (mk[0]) tl =  31 - __builtin_clz(mk[0]);
            else            tl = -1;
            Tl[tid] = tl;
        }
        __syncthreads();
        const int wid = tid >> 6, lane = tid & 63;
        const int st = lane & 15, q = lane >> 4;
        if (wid < 2) {
            char* HsB = (char*)HsW[wid];
            { uint4v z = {0,0,0,0};
              *(uint4v*)(HsB + lane * 32) = z; *(uint4v*)(HsB + lane * 32 + 16) = z; }
            int sc = seq0 + 16 * wid + st; if (sc >= B) sc = B - 1;
            const float* xs = x + (size_t)sc * GK;
            short8 wxf[4][2], whf[4][2]; f32x4 biasv[4];
#pragma unroll
            for (int n = 0; n < 4; ++n) {
                const float* wr_ = Wih + (size_t)(16 * n + st) * FAN;
                wxf[n][0] = wfragX(wr_, q * 8);
                wxf[n][1] = wfragX(wr_, 32 + q * 8);
                whf[n][0] = wfragH(wr_ + D_IN, q * 8);
                whf[n][1] = wfragH(wr_ + D_IN, 32 + q * 8);
#pragma unroll
                for (int jj = 0; jj < 4; ++jj) biasv[n][jj] = bih[16 * n + 4 * q + jj];
            }
            const unsigned rb0 = (unsigned)(128 * st + 16 * q);
            const unsigned rb1 = (unsigned)(128 * st + 64 + 16 * q);
            unsigned wb[4];
#pragma unroll
            for (int n = 0; n < 4; ++n) wb[n] = (unsigned)(128 * st + 32 * n + 8 * q);
            unsigned mkw[4] = { Mm[16 * wid + st][0], Mm[16 * wid + st][1],
                                Mm[16 * wid + st][2], Mm[16 * wid + st][3] };
            f32x4 hcur[4], hpre[4];
#pragma unroll
            for (int n = 0; n < 4; ++n) { hcur[n] = (f32x4){0,0,0,0}; hpre[n] = (f32x4){0,0,0,0}; }
#pragma unroll 1
            for (int t = 0; t < T_STEPS; ++t) {
                XR r; loadx(r, xs, t, q);
                FragU bh0, bh1;
                bh0.u4 = *(const uint4v*)(HsB + rb0);
                bh1.u4 = *(const uint4v*)(HsB + rb1);
                short8 bx0 = xfrag(r.a), bx1 = xfrag(r.b);
                f32x4 acc[4];
#pragma unroll
                for (int n = 0; n < 4; ++n) {
                    f32x4 cc2 = biasv[n];
                    cc2 = MFMA(wxf[n][0], bx0, cc2);
                    cc2 = MFMA(wxf[n][1], bx1, cc2);
                    cc2 = MFMA(whf[n][0], bh0.s8, cc2);
                    cc2 = MFMA(whf[n][1], bh1.s8, cc2);
                    acc[n] = cc2;
                }
                bool v = ((mkw[t >> 5] >> (t & 31)) & 1u) != 0;
#pragma unroll
                for (int n = 0; n < 4; ++n)
#pragma unroll
                    for (int jj = 0; jj < 4; ++jj) {
                        float o = hcur[n][jj];
                        hpre[n][jj] = v ? o : hpre[n][jj];
                        hcur[n][jj] = v ? acc[n][jj] : o;
                    }
#pragma unroll
                for (int n = 0; n < 4; ++n) {
                    uint2v w2;
                    w2[0] = pk2(hcur[n][0], hcur[n][1]);
                    w2[1] = pk2(hcur[n][2], hcur[n][3]);
                    *(uint2v*)(HsB + wb[n]) = w2;
                }
                DS_FENCE();
            }
#pragma unroll
            for (int n = 0; n < 4; ++n)
                *(f32x4*)&Hp[16 * wid + st][16 * n + 4 * q] = hpre[n];
        }
        __syncthreads();
    }

    {
        int s = tid >> 3, p = tid & 7;
        int seq = seq0 + s;
        int t_l = Tl[s];
        if (p < ODIM) {
            float a = 0.0f;
            if (seq < B && t_l >= 0) {
                const float* xr = x + (size_t)seq * GK + (size_t)t_l * D_IN;
                const float* wo = Wio + p * FAN;
                a = bio[p];
                for (int k = 0; k < D_IN; ++k) a += xr[k] * wo[k];
                for (int k = 0; k < HDIM; ++k) a += Hp[s][k] * wo[D_IN + k];
            }
            Lg[s][p] = a;
        }
    }
    __syncthreads();
    if (tid < 32) {
        int s = tid, seq = seq0 + s;
        if (seq < B) {
            float* op = out + (size_t)seq * ODIM;
            if (Tl[s] < 0) {
#pragma unroll
                for (int o = 0; o < ODIM; ++o) op[o] = 0.0f;
            } else {
                float m = Lg[s][0];
#pragma unroll
                for (int o = 1; o < ODIM; ++o) m = fmaxf(m, Lg[s][o]);
                float sum = 0.0f;
#pragma unroll
                for (int o = 0; o < ODIM; ++o) sum += expf(Lg[s][o] - m);
                float lse = m + logf(sum);
#pragma unroll
                for (int o = 0; o < ODIM; ++o) op[o] = Lg[s][o] - lse;
            }
        }
    }
}

extern "C" void kernel_launch(void* const* d_in, const int* in_sizes, int n_in,
                              void* d_out, int out_size, void* d_ws, size_t ws_size,
                              hipStream_t stream)
{
    const float* x     = (const float*)d_in[0];
    const float* W_i2h = (const float*)d_in[1];
    const float* b_i2h = (const float*)d_in[2];
    const float* W_i2o = (const float*)d_in[3];
    const float* b_i2o = (const float*)d_in[4];
    float* out = (float*)d_out;
    char*  wsb = (char*)d_ws;

    const int B = in_sizes[0] / (T_STEPS * D_IN);
    const int ngroups = (B + 31) / 32;
    const int nmain   = 2 * ngroups;

    float* Hpart = (float*)(wsb + GBYTES + 256);
    int*   flags = (int*)(wsb + GBYTES + 256 + (size_t)nmain * 2048 * 4);

    hipLaunchKernelGGL(rnn_prep,      dim3(128),     dim3(512),  0, stream, W_i2h, b_i2h, wsb);
    hipLaunchKernelGGL(rnn_gemm_half, dim3(nmain),   dim3(1024), 0, stream,
                       x, (const char*)wsb, Hpart, flags, B);
    hipLaunchKernelGGL(rnn_epilogue,  dim3(ngroups), dim3(256),  0, stream,
                       x, W_i2h, b_i2h, W_i2o, b_i2o, (const char*)wsb,
                       (const float*)Hpart, (const int*)flags, out, B);
}

// Round 15
// 47.030 us; speedup vs baseline: 1.0543x; 1.0543x over previous
//
#include <hip/hip_runtime.h>
#include <cstddef>

#define T_STEPS 128
#define D_IN    57
#define HDIM    64
#define ODIM    7
#define FAN     121
#define GK      7296          // floats per x row (128*57)
#define KTOT    7239          // 127*57 real G columns
#define KHALF   3648          // 64*57
#define GBYTES  ((size_t)HDIM * GK * 2)

typedef __attribute__((ext_vector_type(8))) short    short8;
typedef __attribute__((ext_vector_type(4))) float    f32x4;
typedef __attribute__((ext_vector_type(4))) unsigned uint4v;
typedef __attribute__((ext_vector_type(2))) unsigned uint2v;

#define MFMA(a,b,c) __builtin_amdgcn_mfma_f32_16x16x32_bf16((a),(b),(c),0,0,0)
#define DS_FENCE()  __builtin_amdgcn_sched_barrier(0x7F)

union FragU { short8 s8; unsigned u[4]; uint4v u4; };

__device__ inline unsigned short f2bf(float f) {
    __bf16 h = (__bf16)f;
    return __builtin_bit_cast(unsigned short, h);
}
__device__ inline float bf2f(unsigned short u) {
    return __builtin_bit_cast(float, (unsigned)u << 16);
}
__device__ inline unsigned pk2(float lo, float hi) {
    return ((unsigned)f2bf(hi) << 16) | (unsigned)f2bf(lo);
}
__device__ inline unsigned swz(unsigned b) {
    return b ^ (((b >> 7) & 7u) << 4);
}

// G fragment-linear byte offset for element (h, k)
__device__ inline size_t gfrag_off(int h, int k) {
    int ch = k >> 5, kk = k & 31;
    return (size_t)(((ch * 4 + (h >> 4)) * 64 + (kk >> 3) * 16 + (h & 15)) * 16 + (kk & 7) * 2);
}

__device__ inline short8 wfragX(const float* Wr, int kbase) {
    FragU f;
#pragma unroll
    for (int d = 0; d < 4; ++d) {
        int k0 = kbase + 2 * d, k1 = k0 + 1;
        float a = (k0 < D_IN) ? Wr[k0] : 0.0f;
        float b = (k1 < D_IN) ? Wr[k1] : 0.0f;
        f.u[d] = pk2(a, b);
    }
    return f.s8;
}
__device__ inline short8 wfragH(const float* Wr, int kbase) {
    FragU f;
#pragma unroll
    for (int d = 0; d < 4; ++d) { int k0 = kbase + 2 * d; f.u[d] = pk2(Wr[k0], Wr[k0 + 1]); }
    return f.s8;
}
__device__ inline short8 xfrag(const float* r) {
    FragU f;
#pragma unroll
    for (int d = 0; d < 4; ++d) f.u[d] = pk2(r[2 * d], r[2 * d + 1]);
    return f.s8;
}

struct XR { float a[8]; float b[8]; };
__device__ inline void loadx(XR& r, const float* xrow, int t, int q) {
    const float* p = xrow + t * D_IN;
#pragma unroll
    for (int i = 0; i < 8; ++i) r.a[i] = p[q * 8 + i];
    if (q == 3) {
        r.b[0] = p[56];
#pragma unroll
        for (int i = 1; i < 8; ++i) r.b[i] = 0.0f;
    } else {
#pragma unroll
        for (int i = 0; i < 8; ++i) r.b[i] = p[32 + q * 8 + i];
    }
}

// ===== prep (128 blocks): unchanged from R13 (fragment-linear G writeback) =====
__global__ __launch_bounds__(512, 1) void rnn_prep(
    const float* __restrict__ Wih, const float* __restrict__ bih, char* __restrict__ wsb)
{
    float* Sb = (float*)(wsb + GBYTES);
    const int t    = blockIdx.x;
    const int n    = 126 - t;
    const int tid  = threadIdx.x;
    const int lane = tid & 63, wid = tid >> 6;
    const int st   = lane & 15, q = lane >> 4;

    __shared__ __align__(16) unsigned short Arow[2][64][64];
    __shared__ __align__(16) unsigned short Acol[2][64][64];
    __shared__ __align__(16) unsigned short Ccol[2][64][64];
    __shared__ float Ub[64], Wb[64], Ptu[64][8], Ptw[64][8];

    {
        const int h  = tid & 63;
        const int k0 = (tid >> 6) * 8;
        unsigned ur[4], uc[4], ux[4];
#pragma unroll
        for (int d = 0; d < 4; ++d) {
            ur[d] = pk2(Wih[h * FAN + D_IN + k0 + 2 * d], Wih[h * FAN + D_IN + k0 + 2 * d + 1]);
            uc[d] = pk2(Wih[(k0 + 2 * d) * FAN + D_IN + h], Wih[(k0 + 2 * d + 1) * FAN + D_IN + h]);
            float e0 = (h < D_IN) ? Wih[(k0 + 2 * d) * FAN + h] : 0.0f;
            float e1 = (h < D_IN) ? Wih[(k0 + 2 * d + 1) * FAN + h] : 0.0f;
            ux[d] = pk2(e0, e1);
        }
        uint4v v;
        v[0] = ur[0]; v[1] = ur[1]; v[2] = ur[2]; v[3] = ur[3];
        *(uint4v*)((char*)Arow[0] + swz((unsigned)(h * 128 + k0 * 2))) = v;
        v[0] = uc[0]; v[1] = uc[1]; v[2] = uc[2]; v[3] = uc[3];
        *(uint4v*)((char*)Acol[0] + swz((unsigned)(h * 128 + k0 * 2))) = v;
        v[0] = ux[0]; v[1] = ux[1]; v[2] = ux[2]; v[3] = ux[3];
        *(uint4v*)((char*)Ccol[0] + swz((unsigned)(h * 128 + k0 * 2))) = v;
    }
    if (tid < 64) { Ub[tid] = bih[tid]; Wb[tid] = bih[tid]; }
    __syncthreads();

    int ab = 0, cb = 0;
    for (int i = 0; i < 7; ++i) {
        const bool domul = (t < 127) && ((n >> i) & 1);
        const bool dosq  = (i < 6);
        const char* Lr = (const char*)Arow[ab];
        f32x4 accM[2], accS[2];
#pragma unroll
        for (int e = 0; e < 2; ++e) {
            const int tt = wid * 2 + e, r = tt >> 2, c = tt & 3;
            FragU a0, a1;
            a0.u4 = *(const uint4v*)(Lr + swz((unsigned)((16 * r + st) * 128 + q * 16)));
            a1.u4 = *(const uint4v*)(Lr + swz((unsigned)((16 * r + st) * 128 + 64 + q * 16)));
            if (domul) {
                FragU b0, b1;
                b0.u4 = *(const uint4v*)((const char*)Ccol[cb] + swz((unsigned)((16 * c + st) * 128 + q * 16)));
                b1.u4 = *(const uint4v*)((const char*)Ccol[cb] + swz((unsigned)((16 * c + st) * 128 + 64 + q * 16)));
                f32x4 z = {0.f, 0.f, 0.f, 0.f};
                accM[e] = MFMA(a0.s8, b0.s8, z);
                accM[e] = MFMA(a1.s8, b1.s8, accM[e]);
            }
            if (dosq) {
                FragU b0, b1;
                b0.u4 = *(const uint4v*)((const char*)Acol[ab] + swz((unsigned)((16 * c + st) * 128 + q * 16)));
                b1.u4 = *(const uint4v*)((const char*)Acol[ab] + swz((unsigned)((16 * c + st) * 128 + 64 + q * 16)));
                f32x4 z = {0.f, 0.f, 0.f, 0.f};
                accS[e] = MFMA(a0.s8, b0.s8, z);
                accS[e] = MFMA(a1.s8, b1.s8, accS[e]);
            }
        }
        if (t == 127) {
            const int h = tid >> 3, p = tid & 7;
            FragU sr;
            sr.u4 = *(const uint4v*)(Lr + swz((unsigned)(h * 128 + p * 16)));
            float su = 0.0f, sw = 0.0f;
#pragma unroll
            for (int d2 = 0; d2 < 4; ++d2) {
                float e0 = bf2f((unsigned short)(sr.u[d2] & 0xFFFFu));
                float e1 = bf2f((unsigned short)(sr.u[d2] >> 16));
                su += e0 * Ub[8 * p + 2 * d2] + e1 * Ub[8 * p + 2 * d2 + 1];
                sw += e0 * Wb[8 * p + 2 * d2] + e1 * Wb[8 * p + 2 * d2 + 1];
            }
            Ptu[h][p] = su; Ptw[h][p] = sw;
        }
        if (domul) {
#pragma unroll
            for (int e = 0; e < 2; ++e) {
                const int tt = wid * 2 + e, r = tt >> 2, c = tt & 3;
                uint2v w; w[0] = pk2(accM[e][0], accM[e][1]); w[1] = pk2(accM[e][2], accM[e][3]);
                *(uint2v*)((char*)Ccol[cb ^ 1] + swz((unsigned)((16 * c + st) * 128 + (16 * r + 4 * q) * 2))) = w;
            }
        }
        if (dosq) {
#pragma unroll
            for (int e = 0; e < 2; ++e) {
                const int tt = wid * 2 + e, r = tt >> 2, c = tt & 3;
                uint2v w; w[0] = pk2(accS[e][0], accS[e][1]); w[1] = pk2(accS[e][2], accS[e][3]);
                *(uint2v*)((char*)Acol[ab ^ 1] + swz((unsigned)((16 * c + st) * 128 + (16 * r + 4 * q) * 2))) = w;
#pragma unroll
                for (int j = 0; j < 4; ++j)
                    *(unsigned short*)((char*)Arow[ab ^ 1]
                        + swz((unsigned)((16 * r + 4 * q + j) * 128 + (16 * c + st) * 2))) = f2bf(accS[e][j]);
            }
        }
        __syncthreads();
        if (t == 127) {
            if (tid < 64) {
                float su = Ub[tid], sw = 0.0f;
#pragma unroll
                for (int p = 0; p < 8; ++p) { su += Ptu[tid][p]; sw += Ptw[tid][p]; }
                Ub[tid] = su;
                Wb[tid] = sw;
            }
            __syncthreads();
        }
        if (domul) cb ^= 1;
        if (dosq)  ab ^= 1;
    }

    if (t < 127) {
        for (int idx = tid; idx < 64 * D_IN; idx += 512) {
            int h = idx / D_IN, c = idx - h * D_IN;
            unsigned short val =
                *(const unsigned short*)((const char*)Ccol[cb] + swz((unsigned)(c * 128 + h * 2)));
            *(unsigned short*)(wsb + gfrag_off(h, 57 * t + c)) = val;
        }
    } else {
        if (tid < 64) Sb[tid] = Ub[tid] - Wb[tid];
        for (int idx = tid; idx < 64 * (GK - KTOT); idx += 512) {
            int h = idx / (GK - KTOT), c = idx % (GK - KTOT);
            *(unsigned short*)(wsb + gfrag_off(h, KTOT + c)) = 0;
        }
    }
}

// ===== main: (16 seqs) x (K half); R13 structure + XCD-pair swizzle (halves share one L2) =====
__global__ __launch_bounds__(1024, 8) void rnn_gemm_half(
    const float* __restrict__ x,
    const char*  __restrict__ wsb,
    float* __restrict__ Hpart,
    int*   __restrict__ flags,
    int B)
{
    const int tid  = threadIdx.x;
    const int wid  = tid >> 6, lane = tid & 63;
    const int st   = lane & 15, q = lane >> 4;

    // XCD swizzle: dispatch id b -> XCD b%8 (round-robin). Remap so each XCD
    // owns a contiguous chunk of logical ids; pairs (2g,2g+1) stay on one XCD.
    int lb;
    {
        int b = blockIdx.x, nb = gridDim.x;
        if ((nb & 7) == 0) { int per = nb >> 3; lb = (b & 7) * per + (b >> 3); }
        else lb = b;
    }
    const int half = lb & 1;
    const int grp  = lb >> 1;
    const int seq0 = grp * 16;

    __shared__ __align__(16) char XsB[2][16384];   // staged x tile, bf16 frag-order, 2 bufs
    __shared__ float Red[8][1024];                 // 32 KB
    __shared__ int   FlgL;

    if (tid == 0) FlgL = (seq0 + 16 > B) ? 1 : 0;  // partial group -> force slow path

    int seqw = seq0 + wid; if (seqw >= B) seqw = B - 1;
    const float* xsw = x + (size_t)seqw * GK;
    const int tbase0 = half * KHALF;

    bool vflag = false;
    f32x4 sxa, sxb; bool sact = false;
    const int sc_ = lane >> 2, sq_ = lane & 3;     // staging (chunk, quarter) of this lane

    auto SLOAD = [&](int tile) {
        int nc = (tile < 7) ? 16 : 2;
        sact = (sc_ < nc);
        if (sact) {
            int k0 = tbase0 + tile * 512 + sc_ * 32 + sq_ * 8;
            sxa = *(const f32x4*)(xsw + k0);
            sxb = *(const f32x4*)(xsw + k0 + 4);
        }
    };
    auto SWRITE = [&](int tile, int buf) {
        if (sact) {
            int k0 = tbase0 + tile * 512 + sc_ * 32 + sq_ * 8;
            int r  = k0 % 57;
            int e  = (r == 0) ? 0 : 57 - r;
            if (e < 8) {
                float v = (e == 0) ? sxa[0] : (e == 1) ? sxa[1] : (e == 2) ? sxa[2]
                        : (e == 3) ? sxa[3] : (e == 4) ? sxb[0] : (e == 5) ? sxb[1]
                        : (e == 6) ? sxb[2] : sxb[3];
                vflag |= (v == -1.0f);
            }
            uint4v wv;
            wv[0] = pk2(sxa[0], sxa[1]); wv[1] = pk2(sxa[2], sxa[3]);
            wv[2] = pk2(sxb[0], sxb[1]); wv[3] = pk2(sxb[2], sxb[3]);
            unsigned a = ((unsigned)((sc_ * 64 + sq_ * 16 + wid) * 16)) ^ ((unsigned)(sc_ & 7) << 4);
            *(uint4v*)(&XsB[buf][a]) = wv;
        }
    };

    f32x4 acc[4];
#pragma unroll
    for (int n = 0; n < 4; ++n) acc[n] = (f32x4){0, 0, 0, 0};

    SLOAD(0); SWRITE(0, 0);
    __syncthreads();

#pragma unroll 1
    for (int tile = 0; tile < 8; ++tile) {
        int buf = tile & 1;
        if (tile + 1 < 8) SLOAD(tile + 1);
        int nc = (tile < 7) ? 16 : 2;
        if (wid < nc) {
            unsigned a = ((unsigned)((wid * 64 + lane) * 16)) ^ ((unsigned)(wid & 7) << 4);
            FragU bx; bx.u4 = *(const uint4v*)(&XsB[buf][a]);
            int cabs = half * 114 + tile * 16 + wid;
            const char* gb = wsb + ((size_t)cabs << 12);    // cabs*4 units of 1024B
            FragU a0, a1, a2, a3;
            a0.u4 = *(const uint4v*)(gb + 0 * 1024 + lane * 16);
            a1.u4 = *(const uint4v*)(gb + 1 * 1024 + lane * 16);
            a2.u4 = *(const uint4v*)(gb + 2 * 1024 + lane * 16);
            a3.u4 = *(const uint4v*)(gb + 3 * 1024 + lane * 16);
            acc[0] = MFMA(a0.s8, bx.s8, acc[0]);
            acc[1] = MFMA(a1.s8, bx.s8, acc[1]);
            acc[2] = MFMA(a2.s8, bx.s8, acc[2]);
            acc[3] = MFMA(a3.s8, bx.s8, acc[3]);
        }
        if (tile + 1 < 8) SWRITE(tile + 1, buf ^ 1);
        __syncthreads();
    }

    if (vflag) atomicOr(&FlgL, 1);

    // two-round reduction (Red = 8 arrays)
    if (wid < 8) {
#pragma unroll
        for (int n = 0; n < 4; ++n)
#pragma unroll
            for (int jj = 0; jj < 4; ++jj)
                Red[wid][(16 * n + 4 * q + jj) * 16 + st] = acc[n][jj];
    }
    __syncthreads();
    if (wid >= 8) {
#pragma unroll
        for (int n = 0; n < 4; ++n)
#pragma unroll
            for (int jj = 0; jj < 4; ++jj)
                Red[wid - 8][(16 * n + 4 * q + jj) * 16 + st] += acc[n][jj];
    }
    __syncthreads();
    {
        float s = 0;
#pragma unroll
        for (int w = 0; w < 8; ++w) s += Red[w][tid];
        Hpart[(size_t)lb * 1024 + tid] = s;     // keyed by LOGICAL id
    }
    if (tid == 0) flags[lb] = FlgL;
}

// ===== epilogue (grid = ngroups, 256 thr) — unchanged from R13 =====
__global__ __launch_bounds__(256, 1) void rnn_epilogue(
    const float* __restrict__ x,
    const float* __restrict__ Wih,
    const float* __restrict__ bih,
    const float* __restrict__ Wio,
    const float* __restrict__ bio,
    const char*  __restrict__ wsb,
    const float* __restrict__ Hpart,
    const int*   __restrict__ flags,
    float* __restrict__ out,
    int B)
{
    const float* Sb = (const float*)(wsb + GBYTES);
    const int grp  = blockIdx.x;
    const int seq0 = grp * 16;
    const int tid  = threadIdx.x;

    __shared__ float Hp[16][68];
    __shared__ float Lg[16][8];
    __shared__ int   Tl[16];
    __shared__ unsigned char Mb[16][16];
    __shared__ unsigned Mm[16][4];
    __shared__ __align__(16) unsigned short HsW[1024];

    const float* p0 = Hpart + (size_t)(2 * grp)     * 1024;
    const float* p1 = Hpart + (size_t)(2 * grp + 1) * 1024;
    for (int i = tid; i < 1024; i += 256) {
        int hid = i >> 4, sl = i & 15;
        Hp[sl][hid] = p0[i] + p1[i] + Sb[hid];
    }
    if (tid < 16) Tl[tid] = 127;
    const int bad = flags[2 * grp] | flags[2 * grp + 1];
    __syncthreads();

    if (bad) {
        {
            int sl = tid & 15, tg = tid >> 4;
            int sc = seq0 + sl; if (sc >= B) sc = B - 1;
            const float* xr = x + (size_t)sc * GK;
            unsigned m = 0;
#pragma unroll
            for (int i = 0; i < 8; ++i)
                m |= ((xr[(size_t)(8 * tg + i) * D_IN] != -1.0f) ? 1u : 0u) << i;
            Mb[sl][tg] = (unsigned char)m;
        }
        __syncthreads();
        if (tid < 16) {
            unsigned mk[4];
#pragma unroll
            for (int j = 0; j < 4; ++j)
                mk[j] = (unsigned)Mb[tid][4 * j]
                      | ((unsigned)Mb[tid][4 * j + 1] << 8)
                      | ((unsigned)Mb[tid][4 * j + 2] << 16)
                      | ((unsigned)Mb[tid][4 * j + 3] << 24);
            Mm[tid][0] = mk[0]; Mm[tid][1] = mk[1]; Mm[tid][2] = mk[2]; Mm[tid][3] = mk[3];
            int tl;
            if (mk[3])      tl = 127 - __builtin_clz(mk[3]);
            else if (mk[2]) tl =  95 - __builtin_clz(mk[2]);
            else if (mk[1]) tl =  63 - __builtin_clz(mk[1]);
            else if (mk[0]) tl =  31 - __builtin_clz(mk[0]);
            else            tl = -1;
            Tl[tid] = tl;
        }
        __syncthreads();
        const int wid = tid >> 6, lane = tid & 63;
        const int st = lane & 15, q = lane >> 4;
        if (wid == 0) {
            char* HsB = (char*)HsW;
            { uint4v z = {0,0,0,0};
              *(uint4v*)(HsB + lane * 32) = z; *(uint4v*)(HsB + lane * 32 + 16) = z; }
            int sc = seq0 + st; if (sc >= B) sc = B - 1;
            const float* xs = x + (size_t)sc * GK;
            short8 wxf[4][2], whf[4][2]; f32x4 biasv[4];
#pragma unroll
            for (int n = 0; n < 4; ++n) {
                const float* wr_ = Wih + (size_t)(16 * n + st) * FAN;
                wxf[n][0] = wfragX(wr_, q * 8);
                wxf[n][1] = wfragX(wr_, 32 + q * 8);
                whf[n][0] = wfragH(wr_ + D_IN, q * 8);
                whf[n][1] = wfragH(wr_ + D_IN, 32 + q * 8);
#pragma unroll
                for (int jj = 0; jj < 4; ++jj) biasv[n][jj] = bih[16 * n + 4 * q + jj];
            }
            const unsigned rb0 = (unsigned)(128 * st + 16 * q);
            const unsigned rb1 = (unsigned)(128 * st + 64 + 16 * q);
            unsigned wb[4];
#pragma unroll
            for (int n = 0; n < 4; ++n) wb[n] = (unsigned)(128 * st + 32 * n + 8 * q);
            unsigned mkw[4] = { Mm[st][0], Mm[st][1], Mm[st][2], Mm[st][3] };
            f32x4 hcur[4], hpre[4];
#pragma unroll
            for (int n = 0; n < 4; ++n) { hcur[n] = (f32x4){0,0,0,0}; hpre[n] = (f32x4){0,0,0,0}; }
#pragma unroll 1
            for (int t = 0; t < T_STEPS; ++t) {
                XR r; loadx(r, xs, t, q);
                FragU bh0, bh1;
                bh0.u4 = *(const uint4v*)(HsB + rb0);
                bh1.u4 = *(const uint4v*)(HsB + rb1);
                short8 bx0 = xfrag(r.a), bx1 = xfrag(r.b);
                f32x4 acc[4];
#pragma unroll
                for (int n = 0; n < 4; ++n) {
                    f32x4 cc2 = biasv[n];
                    cc2 = MFMA(wxf[n][0], bx0, cc2);
                    cc2 = MFMA(wxf[n][1], bx1, cc2);
                    cc2 = MFMA(whf[n][0], bh0.s8, cc2);
                    cc2 = MFMA(whf[n][1], bh1.s8, cc2);
                    acc[n] = cc2;
                }
                bool v = ((mkw[t >> 5] >> (t & 31)) & 1u) != 0;
#pragma unroll
                for (int n = 0; n < 4; ++n)
#pragma unroll
                    for (int jj = 0; jj < 4; ++jj) {
                        float o = hcur[n][jj];
                        hpre[n][jj] = v ? o : hpre[n][jj];
                        hcur[n][jj] = v ? acc[n][jj] : o;
                    }
#pragma unroll
                for (int n = 0; n < 4; ++n) {
                    uint2v w2;
                    w2[0] = pk2(hcur[n][0], hcur[n][1]);
                    w2[1] = pk2(hcur[n][2], hcur[n][3]);
                    *(uint2v*)(HsB + wb[n]) = w2;
                }
                DS_FENCE();
            }
#pragma unroll
            for (int n = 0; n < 4; ++n)
                *(f32x4*)&Hp[st][16 * n + 4 * q] = hpre[n];
        }
        __syncthreads();
    }

    if (tid < 128) {
        int s = tid >> 3, p = tid & 7;
        int seq = seq0 + s;
        int t_l = Tl[s];
        if (p < ODIM) {
            float a = 0.0f;
            if (seq < B && t_l >= 0) {
                const float* xr = x + (size_t)seq * GK + (size_t)t_l * D_IN;
                const float* wo = Wio + p * FAN;
                a = bio[p];
                for (int k = 0; k < D_IN; ++k) a += xr[k] * wo[k];
                for (int k = 0; k < HDIM; ++k) a += Hp[s][k] * wo[D_IN + k];
            }
            Lg[s][p] = a;
        }
    }
    __syncthreads();
    if (tid < 16) {
        int s = tid, seq = seq0 + s;
        if (seq < B) {
            float* op = out + (size_t)seq * ODIM;
            if (Tl[s] < 0) {
#pragma unroll
                for (int o = 0; o < ODIM; ++o) op[o] = 0.0f;
            } else {
                float m = Lg[s][0];
#pragma unroll
                for (int o = 1; o < ODIM; ++o) m = fmaxf(m, Lg[s][o]);
                float sum = 0.0f;
#pragma unroll
                for (int o = 0; o < ODIM; ++o) sum += expf(Lg[s][o] - m);
                float lse = m + logf(sum);
#pragma unroll
                for (int o = 0; o < ODIM; ++o) op[o] = Lg[s][o] - lse;
            }
        }
    }
}

extern "C" void kernel_launch(void* const* d_in, const int* in_sizes, int n_in,
                              void* d_out, int out_size, void* d_ws, size_t ws_size,
                              hipStream_t stream)
{
    const float* x     = (const float*)d_in[0];
    const float* W_i2h = (const float*)d_in[1];
    const float* b_i2h = (const float*)d_in[2];
    const float* W_i2o = (const float*)d_in[3];
    const float* b_i2o = (const float*)d_in[4];
    float* out = (float*)d_out;
    char*  wsb = (char*)d_ws;

    const int B = in_sizes[0] / (T_STEPS * D_IN);
    const int ngroups = (B + 15) / 16;
    const int nmain   = 2 * ngroups;

    float* Hpart = (float*)(wsb + GBYTES + 256);
    int*   flags = (int*)(wsb + GBYTES + 256 + (size_t)nmain * 1024 * 4);

    hipLaunchKernelGGL(rnn_prep,      dim3(128),     dim3(512),  0, stream, W_i2h, b_i2h, wsb);
    hipLaunchKernelGGL(rnn_gemm_half, dim3(nmain),   dim3(1024), 0, stream,
                       x, (const char*)wsb, Hpart, flags, B);
    hipLaunchKernelGGL(rnn_epilogue,  dim3(ngroups), dim3(256),  0, stream,
                       x, W_i2h, b_i2h, W_i2o, b_i2o, (const char*)wsb,
                       (const float*)Hpart, (const int*)flags, out, B);
}